// Round 11
// baseline (41.023 us; speedup 1.0000x reference)
//
#include <hip/hip_runtime.h>
#include <math.h>

#define LAMBDA_DECAY 0.01f
#define ALPHA 0.95f
#define LN_EPS 1e-5f

// Geometry (reference: M=8192, D=4096).
#define NB 1024      // K1 blocks
#define RPB 8        // rows per block = M/NB
#define WPB 4        // waves per block (256 threads); wave owns D/4 = 1024 cols
#define G2 128       // partials per K2 block
#define NP2 8        // NB/G2

typedef float v4f __attribute__((ext_vector_type(4)));

static __device__ __forceinline__ float wave_sum_all(float v) {
#pragma unroll
    for (int o = 32; o > 0; o >>= 1) v += __shfl_xor(v, o);
    return v;
}

static __device__ float block_sum(float v, float* sh, int nwaves) {
    int lane = threadIdx.x & 63;
    int w = threadIdx.x >> 6;
    v = wave_sum_all(v);
    if (lane == 0) sh[w] = v;
    __syncthreads();
    float r = 0.0f;
    for (int i = 0; i < nwaves; ++i) r += sh[i];
    __syncthreads();
    return r;
}

// K1: single pass over states. CHANGE vs R6: 256-thread blocks (4 waves),
// wave owns D/4 = 1024 floats (4 float4/lane), NB=1024 RPB=8.
// Rationale: __syncthreads drains vmcnt(0), so prefetch-across-barrier is
// impossible within a block — latency hiding must come from OTHER resident
// blocks. ~95 VGPR -> ~5 waves/SIMD -> 4-5 independent blocks/CU (vs R6's
// 2), each row has 4 loads/lane in flight, barrier couples only 4 waves.
__global__ __launch_bounds__(256) void fused_kernel(
    const float* __restrict__ states, const float* __restrict__ cur,
    const float* __restrict__ weights, const float* __restrict__ ts,
    const float* __restrict__ t_new,
    float* __restrict__ partial, float* __restrict__ partE, float* __restrict__ partS,
    int M, int D, float scale)
{
    __shared__ float shp[2][WPB];

    const int wid = threadIdx.x >> 6;
    const int lane = threadIdx.x & 63;
    const int r0 = blockIdx.x * RPB;
    const int f4base = wid * 256 + lane;     // float4 index of lane's first elem
    const int rstride = D >> 2;              // row stride in float4 (1024)

    const float tn = t_new[0];

    const v4f* c4 = (const v4f*)cur;
    v4f curp[4];
#pragma unroll
    for (int k = 0; k < 4; ++k) curp[k] = c4[f4base + k * 64];

    // Precompute decayed weights for this block's rows (static indexing).
    float wdec[RPB];
#pragma unroll
    for (int r = 0; r < RPB; ++r)
        wdec[r] = weights[r0 + r] * expf(-LAMBDA_DECAY * fabsf(tn - ts[r0 + r]));

    v4f acc[4];
#pragma unroll
    for (int k = 0; k < 4; ++k) acc[k] = (v4f)(0.0f);

    float E = 0.0f, S = 0.0f;

    const v4f* sp = (const v4f*)states + (size_t)r0 * rstride + f4base;

    v4f rv[2][4];
#pragma unroll
    for (int k = 0; k < 4; ++k) rv[0][k] = sp[k * 64];

#pragma unroll
    for (int r = 0; r < RPB; ++r) {
        const int cb = r & 1;        // compile-time after full unroll
        const int nbuf = cb ^ 1;

        // Prefetch next row (4 loads/lane in flight under this row's compute).
        if (r + 1 < RPB) {
#pragma unroll
            for (int k = 0; k < 4; ++k)
                rv[nbuf][k] = sp[(size_t)(r + 1) * rstride + k * 64];
        }

        // Partial dot over this wave's 1024-float slice (2 chains).
        float d0 = 0.0f, d1 = 0.0f;
#pragma unroll
        for (int k = 0; k < 4; k += 2) {
            const v4f a0 = rv[cb][k], a1 = rv[cb][k + 1];
            d0 = fmaf(a0[0], curp[k][0], d0);     d1 = fmaf(a1[0], curp[k + 1][0], d1);
            d0 = fmaf(a0[1], curp[k][1], d0);     d1 = fmaf(a1[1], curp[k + 1][1], d1);
            d0 = fmaf(a0[2], curp[k][2], d0);     d1 = fmaf(a1[2], curp[k + 1][2], d1);
            d0 = fmaf(a0[3], curp[k][3], d0);     d1 = fmaf(a1[3], curp[k + 1][3], d1);
        }
        const float pd = wave_sum_all(d0 + d1);

        if (lane == 0) shp[cb][wid] = pd;
        __syncthreads();

        float s = (shp[cb][0] + shp[cb][1]) + (shp[cb][2] + shp[cb][3]);
        s *= scale;

        const float e = expf(s);
        const float p = e * wdec[r];
        E += e; S += p;                           // uniform across threads

#pragma unroll
        for (int k = 0; k < 4; ++k) acc[k] += p * rv[cb][k];
    }

    v4f* pb = (v4f*)(partial + (size_t)blockIdx.x * D);
#pragma unroll
    for (int k = 0; k < 4; ++k) pb[f4base + k * 64] = acc[k];
    if (threadIdx.x == 0) {
        partE[blockIdx.x] = E;
        partS[blockIdx.x] = S;
    }
}

// K2: tree-reduce partials NB -> NP2 per column. grid=(D/256, NP2).
__global__ __launch_bounds__(256) void reduce_kernel(
    const float* __restrict__ partial, float* __restrict__ partial2, int D)
{
    const int col = blockIdx.x * 256 + threadIdx.x;
    const int b0 = blockIdx.y * G2;
    float a0 = 0.0f, a1 = 0.0f, a2 = 0.0f, a3 = 0.0f;
    for (int b = 0; b < G2; b += 4) {
        a0 += partial[(size_t)(b0 + b) * D + col];
        a1 += partial[(size_t)(b0 + b + 1) * D + col];
        a2 += partial[(size_t)(b0 + b + 2) * D + col];
        a3 += partial[(size_t)(b0 + b + 3) * D + col];
    }
    partial2[(size_t)blockIdx.y * D + col] = (a0 + a1) + (a2 + a3);
}

// K3: final NP2-way column sum + E/S reduce -> inv; blend; LayerNorm. 1 block.
__global__ __launch_bounds__(1024) void finalize_kernel(
    const float* __restrict__ partial2, const float* __restrict__ partE,
    const float* __restrict__ partS, const float* __restrict__ cur,
    float* __restrict__ out, int D)
{
    __shared__ float sh[16];
    const int tid = threadIdx.x;

    float E = 0.0f, S = 0.0f;
    for (int i = tid; i < NB; i += 1024) { E += partE[i]; S += partS[i]; }
    E = block_sum(E, sh, 16);
    S = block_sum(S, sh, 16);
    const float inv = 1.0f / (S + 1e-9f * E);

    float v[4];
    float s = 0.0f, s2 = 0.0f;
#pragma unroll
    for (int k = 0; k < 4; ++k) {
        const int c = tid + k * 1024;
        float a = 0.0f;
#pragma unroll
        for (int y = 0; y < NP2; ++y) a += partial2[y * D + c];
        const float nv = ALPHA * cur[c] + (1.0f - ALPHA) * (a * inv);
        v[k] = nv;
        s += nv; s2 += nv * nv;
    }
    s = block_sum(s, sh, 16);
    s2 = block_sum(s2, sh, 16);
    const float mean = s / (float)D;
    const float var = s2 / (float)D - mean * mean;
    const float rstd = 1.0f / sqrtf(var + LN_EPS);
#pragma unroll
    for (int k = 0; k < 4; ++k)
        out[tid + k * 1024] = (v[k] - mean) * rstd;
}

extern "C" void kernel_launch(void* const* d_in, const int* in_sizes, int n_in,
                              void* d_out, int out_size, void* d_ws, size_t ws_size,
                              hipStream_t stream) {
    const float* states     = (const float*)d_in[0];
    const float* weights    = (const float*)d_in[1];
    const float* timestamps = (const float*)d_in[2];
    const float* current    = (const float*)d_in[3];
    // d_in[4] = sensed_state: not used in the output math.
    const float* t_new      = (const float*)d_in[5];
    float* out = (float*)d_out;

    const int M = in_sizes[1];   // 8192
    const int D = in_sizes[3];   // 4096

    float* ws       = (float*)d_ws;
    float* partial  = ws;                              // [NB * D] (16 MiB)
    float* partial2 = partial + (size_t)NB * D;        // [NP2 * D]
    float* partE    = partial2 + (size_t)NP2 * D;      // [NB]
    float* partS    = partE + NB;                      // [NB]

    const float scale = 1.0f / sqrtf((float)D);

    fused_kernel<<<NB, 256, 0, stream>>>(
        states, current, weights, timestamps, t_new,
        partial, partE, partS, M, D, scale);

    {
        dim3 grid(D / 256, NP2);   // (16, 8)
        reduce_kernel<<<grid, 256, 0, stream>>>(partial, partial2, D);
    }

    finalize_kernel<<<1, 1024, 0, stream>>>(partial2, partE, partS, current, out, D);
}